// Round 1
// baseline (1841.028 us; speedup 1.0000x reference)
//
#include <hip/hip_runtime.h>
#include <cstddef>

#define DEV_INLINE __device__ __forceinline__

DEV_INLINE float sigf(float x) { return 1.0f / (1.0f + __expf(-x)); }
DEV_INLINE float tanh_fast(float x) { float e2 = __expf(2.0f * x); return 1.0f - 2.0f / (e2 + 1.0f); }

// ---------------------------------------------------------------------------
// Pass 1: accumulate weighted in-degree (float) and in-edge count (int) per dst
// ---------------------------------------------------------------------------
__global__ __launch_bounds__(256) void k_edge_pass1(const int* __restrict__ ei,
                                                    const float* __restrict__ ew,
                                                    float* __restrict__ deg,
                                                    int* __restrict__ cnt, int E) {
    int e = blockIdx.x * 256 + threadIdx.x;
    if (e >= E) return;
    int d = ei[(size_t)E + e];  // dst row of edge_index
    atomicAdd(deg + d, ew[e]);
    atomicAdd(cnt + d, 1);
}

// deg -> dinv in place (self loop adds 1.0; deg+1 >= 1 so always rsqrt)
__global__ __launch_bounds__(256) void k_dinv(float* __restrict__ deg, int n) {
    int i = blockIdx.x * 256 + threadIdx.x;
    if (i >= n) return;
    deg[i] = rsqrtf(deg[i] + 1.0f);
}

// ---------------------------------------------------------------------------
// Exclusive scan of cnt[0..n) -> rowptr[0..n], single block of 1024 threads
// ---------------------------------------------------------------------------
__global__ __launch_bounds__(1024) void k_scan(const int* __restrict__ cnt,
                                               int* __restrict__ rowptr, int n) {
    __shared__ int sums[1024];
    int t = threadIdx.x;
    int chunk = (n + 1023) >> 10;
    int lo = t * chunk;
    int hi = min(lo + chunk, n);
    int s = 0;
    for (int i = lo; i < hi; i++) s += cnt[i];
    sums[t] = s;
    __syncthreads();
    for (int off = 1; off < 1024; off <<= 1) {
        int v = sums[t];
        int w = (t >= off) ? sums[t - off] : 0;
        __syncthreads();
        sums[t] = v + w;
        __syncthreads();
    }
    int run = (t > 0) ? sums[t - 1] : 0;
    for (int i = lo; i < hi; i++) { rowptr[i] = run; run += cnt[i]; }
    if (lo < n && hi == n) rowptr[n] = run;
}

// ---------------------------------------------------------------------------
// Fill CSR (by dst): csrc[p] = src, ccoef[p] = dinv[src]*w*dinv[dst]
// ---------------------------------------------------------------------------
__global__ __launch_bounds__(256) void k_fill(const int* __restrict__ ei,
                                              const float* __restrict__ ew,
                                              const float* __restrict__ dinv,
                                              const int* __restrict__ rowptr,
                                              int* __restrict__ cursor,
                                              int* __restrict__ csrc,
                                              float* __restrict__ ccoef, int E) {
    int e = blockIdx.x * 256 + threadIdx.x;
    if (e >= E) return;
    int s = ei[e];
    int d = ei[(size_t)E + e];
    float cf = dinv[s] * ew[e] * dinv[d];
    int p = rowptr[d] + atomicAdd(cursor + d, 1);
    csrc[p] = s;
    ccoef[p] = cf;
}

// ---------------------------------------------------------------------------
// Pull aggregation: Xp[d, :] = dinv[d]^2 * X[d, :] + sum_e coef_e * X[src_e, :]
// 4 threads per node, each owns 24 contiguous floats (6 x float4).
// ---------------------------------------------------------------------------
__global__ __launch_bounds__(256) void k_pull(const float* __restrict__ X,
                                              const float* __restrict__ dinv,
                                              const int* __restrict__ rowptr,
                                              const int* __restrict__ csrc,
                                              const float* __restrict__ ccoef,
                                              float* __restrict__ Xp, int n) {
    int gid = blockIdx.x * 256 + threadIdx.x;
    int d = gid >> 2;
    int c = gid & 3;
    if (d >= n) return;
    float di = dinv[d];
    float sl = di * di;
    const float* xr = X + (size_t)d * 96 + c * 24;
    float4 a[6];
#pragma unroll
    for (int q = 0; q < 6; q++) {
        float4 v = *(const float4*)(xr + q * 4);
        a[q].x = sl * v.x; a[q].y = sl * v.y; a[q].z = sl * v.z; a[q].w = sl * v.w;
    }
    int lo = rowptr[d], hi = rowptr[d + 1];
    for (int e = lo; e < hi; e++) {
        int s = csrc[e];
        float cf = ccoef[e];
        const float* xs = X + (size_t)s * 96 + c * 24;
#pragma unroll
        for (int q = 0; q < 6; q++) {
            float4 v = *(const float4*)(xs + q * 4);
            a[q].x += cf * v.x; a[q].y += cf * v.y; a[q].z += cf * v.z; a[q].w += cf * v.w;
        }
    }
    float* o = Xp + (size_t)d * 96 + c * 24;
#pragma unroll
    for (int q = 0; q < 6; q++) *(float4*)(o + q * 4) = a[q];
}

// ---------------------------------------------------------------------------
// Per-node GRU over 12 timesteps, fully in registers; weights via uniform
// (scalar) loads. One thread per node.
// ---------------------------------------------------------------------------
__global__ __launch_bounds__(256) void k_gru(const float* __restrict__ Xp,
                                             const float* __restrict__ x,
                                             const float* __restrict__ Wz, const float* __restrict__ bz,
                                             const float* __restrict__ Wr, const float* __restrict__ br,
                                             const float* __restrict__ Wh, const float* __restrict__ bh,
                                             const float* __restrict__ Lz, const float* __restrict__ lbz,
                                             const float* __restrict__ Lr, const float* __restrict__ lbr,
                                             const float* __restrict__ Lh, const float* __restrict__ lbh,
                                             const float* __restrict__ att,
                                             const float* __restrict__ Wp, const float* __restrict__ bp,
                                             float* __restrict__ out, int n) {
    int i = blockIdx.x * 256 + threadIdx.x;
    if (i >= n) return;

    // softmax(att) pieces (uniform across threads)
    float am = -1e30f;
    for (int t = 0; t < 12; t++) am = fmaxf(am, att[t]);
    float ad = 0.0f;
    for (int t = 0; t < 12; t++) ad += __expf(att[t] - am);
    float inv_ad = 1.0f / ad;

    float H[32], acc[32];
#pragma unroll
    for (int j = 0; j < 32; j++) { H[j] = 0.0f; acc[j] = 0.0f; }

    const float* __restrict__ xrow = Xp + (size_t)i * 96;

#pragma unroll 1
    for (int t = 0; t < 12; t++) {
        float pt = __expf(att[t] - am) * inv_ad;
        float xin[8];
#pragma unroll
        for (int f = 0; f < 8; f++) xin[f] = xrow[f * 12 + t];

        float cz[32], cr[32], ch[32];
#pragma unroll
        for (int j = 0; j < 32; j++) { cz[j] = bz[j]; cr[j] = br[j]; ch[j] = bh[j]; }
#pragma unroll
        for (int f = 0; f < 8; f++) {
            float xf = xin[f];
#pragma unroll
            for (int j = 0; j < 32; j++) {
                cz[j] += xf * Wz[f * 32 + j];
                cr[j] += xf * Wr[f * 32 + j];
                ch[j] += xf * Wh[f * 32 + j];
            }
        }

        // R gate pre-activation -> R*H (stored into rh)
        float rh[32];
#pragma unroll
        for (int j = 0; j < 32; j++) rh[j] = lbr[j];
#pragma unroll
        for (int k = 0; k < 32; k++) {
            float v = cr[k];
#pragma unroll
            for (int j = 0; j < 32; j++) rh[j] += v * Lr[k * 32 + j];
        }
#pragma unroll
        for (int k = 0; k < 32; k++) {
            float v = H[k];
#pragma unroll
            for (int j = 0; j < 32; j++) rh[j] += v * Lr[(32 + k) * 32 + j];
        }
#pragma unroll
        for (int k = 0; k < 32; k++) rh[k] = H[k] * sigf(rh[k]);

        // Z gate pre-activation
        float az[32];
#pragma unroll
        for (int j = 0; j < 32; j++) az[j] = lbz[j];
#pragma unroll
        for (int k = 0; k < 32; k++) {
            float v = cz[k];
#pragma unroll
            for (int j = 0; j < 32; j++) az[j] += v * Lz[k * 32 + j];
        }
#pragma unroll
        for (int k = 0; k < 32; k++) {
            float v = H[k];
#pragma unroll
            for (int j = 0; j < 32; j++) az[j] += v * Lz[(32 + k) * 32 + j];
        }

        // candidate pre-activation (uses rh = R*H)
        float ah[32];
#pragma unroll
        for (int j = 0; j < 32; j++) ah[j] = lbh[j];
#pragma unroll
        for (int k = 0; k < 32; k++) {
            float v = ch[k];
#pragma unroll
            for (int j = 0; j < 32; j++) ah[j] += v * Lh[k * 32 + j];
        }
#pragma unroll
        for (int k = 0; k < 32; k++) {
            float v = rh[k];
#pragma unroll
            for (int j = 0; j < 32; j++) ah[j] += v * Lh[(32 + k) * 32 + j];
        }

#pragma unroll
        for (int j = 0; j < 32; j++) {
            float Zj = sigf(az[j]);
            float T = tanh_fast(ah[j]);
            float h = Zj * H[j] + (1.0f - Zj) * T;
            H[j] = h;
            acc[j] += pt * h;
        }
    }

    float delta = bp[0];
#pragma unroll
    for (int j = 0; j < 32; j++) delta += fmaxf(acc[j], 0.0f) * Wp[j];
    out[i] = fmaxf(delta + x[(size_t)i * 96 + 23], 0.0f);
}

// ---------------------------------------------------------------------------
static inline size_t align_up(size_t v, size_t a) { return (v + a - 1) & ~(a - 1); }

extern "C" void kernel_launch(void* const* d_in, const int* in_sizes, int n_in,
                              void* d_out, int out_size, void* d_ws, size_t ws_size,
                              hipStream_t stream) {
    const float* x   = (const float*)d_in[0];
    const int*   ei  = (const int*)d_in[1];
    const float* ew  = (const float*)d_in[2];
    const float* Wz  = (const float*)d_in[3];
    const float* bz  = (const float*)d_in[4];
    const float* Wr  = (const float*)d_in[5];
    const float* br  = (const float*)d_in[6];
    const float* Wh  = (const float*)d_in[7];
    const float* bh  = (const float*)d_in[8];
    const float* Lz  = (const float*)d_in[9];
    const float* lbz = (const float*)d_in[10];
    const float* Lr  = (const float*)d_in[11];
    const float* lbr = (const float*)d_in[12];
    const float* Lh  = (const float*)d_in[13];
    const float* lbh = (const float*)d_in[14];
    const float* att = (const float*)d_in[15];
    const float* Wp  = (const float*)d_in[16];
    const float* bp  = (const float*)d_in[17];
    float* out = (float*)d_out;

    const int N = in_sizes[0] / 96;   // (N, 8, 12)
    const int E = in_sizes[2];        // edge_weight count

    char* ws = (char*)d_ws;
    size_t off = 0;
    float* deg    = (float*)(ws + off); off = align_up(off + (size_t)N * 4, 256);
    int*   cnt    = (int*)  (ws + off); off = align_up(off + (size_t)N * 4, 256);
    int*   cursor = (int*)  (ws + off); off = align_up(off + (size_t)N * 4, 256);
    int*   rowptr = (int*)  (ws + off); off = align_up(off + (size_t)(N + 1) * 4, 256);
    int*   csrc   = (int*)  (ws + off); off = align_up(off + (size_t)E * 4, 256);
    float* ccoef  = (float*)(ws + off); off = align_up(off + (size_t)E * 4, 256);
    float* Xp     = (float*)(ws + off); off = align_up(off + (size_t)N * 96 * 4, 256);

    // zero deg / cnt / cursor (three contiguous N-word regions would need one
    // memset each since they are aligned separately)
    hipMemsetAsync(deg, 0, (size_t)N * 4, stream);
    hipMemsetAsync(cnt, 0, (size_t)N * 4, stream);
    hipMemsetAsync(cursor, 0, (size_t)N * 4, stream);

    int eb = (E + 255) / 256;
    int nb = (N + 255) / 256;

    k_edge_pass1<<<eb, 256, 0, stream>>>(ei, ew, deg, cnt, E);
    k_dinv<<<nb, 256, 0, stream>>>(deg, N);                 // deg now holds dinv
    k_scan<<<1, 1024, 0, stream>>>(cnt, rowptr, N);
    k_fill<<<eb, 256, 0, stream>>>(ei, ew, deg, rowptr, cursor, csrc, ccoef, E);
    k_pull<<<(N * 4 + 255) / 256, 256, 0, stream>>>(x, deg, rowptr, csrc, ccoef, Xp, N);
    k_gru<<<nb, 256, 0, stream>>>(Xp, x, Wz, bz, Wr, br, Wh, bh,
                                  Lz, lbz, Lr, lbr, Lh, lbh, att, Wp, bp, out, N);
}

// Round 2
// 894.498 us; speedup vs baseline: 2.0582x; 2.0582x over previous
//
#include <hip/hip_runtime.h>
#include <cstddef>

typedef __attribute__((ext_vector_type(8))) short bf16x8;
typedef __attribute__((ext_vector_type(4))) float f32x4;

#define MFMA_B16(a, b, c) __builtin_amdgcn_mfma_f32_16x16x32_bf16(a, b, c, 0, 0, 0)

#define DEV_INLINE __device__ __forceinline__

DEV_INLINE float sigf(float x) { return 1.0f / (1.0f + __expf(-x)); }
DEV_INLINE float tanh_fast(float x) { float e2 = __expf(2.0f * x); return 1.0f - 2.0f / (e2 + 1.0f); }

DEV_INLINE unsigned short f2bf(float f) {
    union { float f; unsigned u; } v; v.f = f;
    unsigned r = v.u + 0x7fffu + ((v.u >> 16) & 1u);
    return (unsigned short)(r >> 16);
}
DEV_INLINE float bflo(unsigned w) { union { unsigned u; float f; } t; t.u = w << 16; return t.f; }
DEV_INLINE float bfhi(unsigned w) { union { unsigned u; float f; } t; t.u = w & 0xffff0000u; return t.f; }

// ---------------------------------------------------------------------------
// Cast x (f32, [N][96] in [f][t] order) -> bf16 copy
// ---------------------------------------------------------------------------
__global__ __launch_bounds__(256) void k_cast(const float* __restrict__ x,
                                              unsigned short* __restrict__ Xb, int n96_4) {
    int i = blockIdx.x * 256 + threadIdx.x;
    if (i >= n96_4) return;
    float4 v = *(const float4*)(x + (size_t)i * 4);
    ushort4 o;
    o.x = f2bf(v.x); o.y = f2bf(v.y); o.z = f2bf(v.z); o.w = f2bf(v.w);
    *(ushort4*)(Xb + (size_t)i * 4) = o;
}

// ---------------------------------------------------------------------------
// Edge pass 1: weighted in-degree + in-edge count
// ---------------------------------------------------------------------------
__global__ __launch_bounds__(256) void k_edge_pass1(const int* __restrict__ ei,
                                                    const float* __restrict__ ew,
                                                    float* __restrict__ deg,
                                                    int* __restrict__ cnt, int E) {
    int e = blockIdx.x * 256 + threadIdx.x;
    if (e >= E) return;
    int d = ei[(size_t)E + e];
    atomicAdd(deg + d, ew[e]);
    atomicAdd(cnt + d, 1);
}

__global__ __launch_bounds__(256) void k_dinv(float* __restrict__ deg, int n) {
    int i = blockIdx.x * 256 + threadIdx.x;
    if (i >= n) return;
    deg[i] = rsqrtf(deg[i] + 1.0f);
}

// ---------------------------------------------------------------------------
// Exclusive scan (single block)
// ---------------------------------------------------------------------------
__global__ __launch_bounds__(1024) void k_scan(const int* __restrict__ cnt,
                                               int* __restrict__ rowptr, int n) {
    __shared__ int sums[1024];
    int t = threadIdx.x;
    int chunk = (n + 1023) >> 10;
    int lo = t * chunk;
    int hi = min(lo + chunk, n);
    int s = 0;
    for (int i = lo; i < hi; i++) s += cnt[i];
    sums[t] = s;
    __syncthreads();
    for (int off = 1; off < 1024; off <<= 1) {
        int v = sums[t];
        int w = (t >= off) ? sums[t - off] : 0;
        __syncthreads();
        sums[t] = v + w;
        __syncthreads();
    }
    int run = (t > 0) ? sums[t - 1] : 0;
    for (int i = lo; i < hi; i++) { rowptr[i] = run; run += cnt[i]; }
    if (lo < n && hi == n) rowptr[n] = run;
}

// ---------------------------------------------------------------------------
// Fill CSR by dst
// ---------------------------------------------------------------------------
__global__ __launch_bounds__(256) void k_fill(const int* __restrict__ ei,
                                              const float* __restrict__ ew,
                                              const float* __restrict__ dinv,
                                              const int* __restrict__ rowptr,
                                              int* __restrict__ cursor,
                                              int* __restrict__ csrc,
                                              float* __restrict__ ccoef, int E) {
    int e = blockIdx.x * 256 + threadIdx.x;
    if (e >= E) return;
    int s = ei[e];
    int d = ei[(size_t)E + e];
    float cf = dinv[s] * ew[e] * dinv[d];
    int p = rowptr[d] + atomicAdd(cursor + d, 1);
    csrc[p] = s;
    ccoef[p] = cf;
}

// ---------------------------------------------------------------------------
// Pull aggregation in bf16. 4 threads/node; thread c owns features f=2c,2c+1
// (elements [c*24, c*24+24) of the [f][t] row). Output Xp is bf16 in
// [node][t*8+f] order (GRU staging layout).
// ---------------------------------------------------------------------------
__global__ __launch_bounds__(256) void k_pull(const unsigned short* __restrict__ Xb,
                                              const float* __restrict__ dinv,
                                              const int* __restrict__ rowptr,
                                              const int* __restrict__ csrc,
                                              const float* __restrict__ ccoef,
                                              unsigned short* __restrict__ Xp, int n) {
    int gid = blockIdx.x * 256 + threadIdx.x;
    int d = gid >> 2;
    int c = gid & 3;
    if (d >= n) return;
    float di = dinv[d];
    float sl = di * di;
    float a[24];
    {
        const unsigned short* xr = Xb + (size_t)d * 96 + c * 24;
#pragma unroll
        for (int q = 0; q < 3; q++) {
            uint4 v = *(const uint4*)(xr + q * 8);
            a[q * 8 + 0] = sl * bflo(v.x); a[q * 8 + 1] = sl * bfhi(v.x);
            a[q * 8 + 2] = sl * bflo(v.y); a[q * 8 + 3] = sl * bfhi(v.y);
            a[q * 8 + 4] = sl * bflo(v.z); a[q * 8 + 5] = sl * bfhi(v.z);
            a[q * 8 + 6] = sl * bflo(v.w); a[q * 8 + 7] = sl * bfhi(v.w);
        }
    }
    int lo = rowptr[d], hi = rowptr[d + 1];
    for (int e = lo; e < hi; e++) {
        int s = csrc[e];
        float cf = ccoef[e];
        const unsigned short* xs = Xb + (size_t)s * 96 + c * 24;
#pragma unroll
        for (int q = 0; q < 3; q++) {
            uint4 v = *(const uint4*)(xs + q * 8);
            a[q * 8 + 0] += cf * bflo(v.x); a[q * 8 + 1] += cf * bfhi(v.x);
            a[q * 8 + 2] += cf * bflo(v.y); a[q * 8 + 3] += cf * bfhi(v.y);
            a[q * 8 + 4] += cf * bflo(v.z); a[q * 8 + 5] += cf * bfhi(v.z);
            a[q * 8 + 6] += cf * bflo(v.w); a[q * 8 + 7] += cf * bfhi(v.w);
        }
    }
    // a[0..11]: f=2c, t=0..11 ; a[12..23]: f=2c+1
    unsigned short* o = Xp + (size_t)d * 96;
#pragma unroll
    for (int t = 0; t < 12; t++) {
        unsigned w = (unsigned)f2bf(a[t]) | ((unsigned)f2bf(a[12 + t]) << 16);
        *(unsigned*)(o + t * 8 + 2 * c) = w;
    }
}

// ---------------------------------------------------------------------------
// Weight precompute: fold input matvec into gate GEMM (swapped layout).
// WC layout (floats):
//   [0,2048)    WZRH_H[64][32] : row j' (0..31 Z, 32..63 R), col k: L{z|r}[32+k][j'&31]
//   [2048,2560) WZR_X [64][8]  : (W{z|r} @ L{z|r}_top)[f][j'&31]
//   [2560,3584) WH_H  [32][32] : Lh[32+k][j]
//   [3584,3840) WH_X  [32][8]  : (Wh @ Lh_top)[f][j]
//   [3840,3904) BZR[64] = b@L_top + lb
//   [3904,3936) BH[32]
// ---------------------------------------------------------------------------
__global__ __launch_bounds__(256) void k_wprep(const float* __restrict__ Wz, const float* __restrict__ Wr,
                                               const float* __restrict__ Wh,
                                               const float* __restrict__ Lz, const float* __restrict__ Lr,
                                               const float* __restrict__ Lh,
                                               const float* __restrict__ bz, const float* __restrict__ br,
                                               const float* __restrict__ bh,
                                               const float* __restrict__ lbz, const float* __restrict__ lbr,
                                               const float* __restrict__ lbh,
                                               float* __restrict__ WC) {
    int tid = threadIdx.x;
    for (int e = tid; e < 2048; e += 256) {
        int j = e >> 5, k = e & 31;
        const float* L = (j < 32) ? Lz : Lr;
        WC[e] = L[(32 + k) * 32 + (j & 31)];
    }
    for (int e = tid; e < 512; e += 256) {
        int j = e >> 3, f = e & 7;
        const float* L = (j < 32) ? Lz : Lr;
        const float* W = (j < 32) ? Wz : Wr;
        int jj = j & 31;
        float s = 0.0f;
        for (int i = 0; i < 32; i++) s += W[f * 32 + i] * L[i * 32 + jj];
        WC[2048 + e] = s;
    }
    for (int e = tid; e < 1024; e += 256) {
        int j = e >> 5, k = e & 31;
        WC[2560 + e] = Lh[(32 + k) * 32 + j];
    }
    for (int e = tid; e < 256; e += 256) {
        int j = e >> 3, f = e & 7;
        float s = 0.0f;
        for (int i = 0; i < 32; i++) s += Wh[f * 32 + i] * Lh[i * 32 + j];
        WC[3584 + e] = s;
    }
    if (tid < 64) {
        int j = tid;
        const float* L = (j < 32) ? Lz : Lr;
        const float* b = (j < 32) ? bz : br;
        const float* lb = (j < 32) ? lbz : lbr;
        int jj = j & 31;
        float s = lb[jj];
        for (int i = 0; i < 32; i++) s += b[i] * L[i * 32 + jj];
        WC[3840 + j] = s;
    }
    if (tid < 32) {
        float s = lbh[tid];
        for (int i = 0; i < 32; i++) s += bh[i] * Lh[i * 32 + tid];
        WC[3904 + tid] = s;
    }
}

// ---------------------------------------------------------------------------
// MFMA GRU: one wave (64 threads) per 64-node tile. Swapped GEMM:
//   D[j'][node] = sum_k A'[j'][k] * B'[k][node]
// A' = weights (loaded once to frags), B' = [H | Xt] from per-wave LDS.
// D layout: node = lane&15 (+16*nt), j' = 16*mt + 4*(lane>>4) + r.
// H state kept f32 in D-layout regs; bf16 copy in sH (stride 40) for B-frags.
// ---------------------------------------------------------------------------
__global__ __launch_bounds__(64, 2) void k_gru(const unsigned short* __restrict__ Xp,
                                               const float* __restrict__ x,
                                               const float* __restrict__ WC,
                                               const float* __restrict__ att,
                                               const float* __restrict__ Wp,
                                               const float* __restrict__ bp,
                                               float* __restrict__ out, int n) {
    __shared__ __align__(16) unsigned short sH[64 * 40];
    __shared__ __align__(16) unsigned short sRH[64 * 40];
    __shared__ __align__(16) unsigned short sXp[12 * 64 * 8];
    __shared__ __align__(16) unsigned short zblk[8];

    const int l = threadIdx.x;
    const int lo16 = l & 15;
    const int g = l >> 4;
    const int base = blockIdx.x * 64;
    const int cnode = min(base + l, n - 1);

    // stage this wave's Xp rows: chunk q of a row == (t=q, f=0..7)
    {
        const unsigned short* xrow = Xp + (size_t)cnode * 96;
#pragma unroll
        for (int q = 0; q < 12; q++) {
            uint4 v = *(const uint4*)(xrow + q * 8);
            *(uint4*)(&sXp[q * 512 + l * 8]) = v;
        }
    }
    // zero H tile + zero block
    for (int i = l; i < 64 * 40 / 2; i += 64) ((unsigned*)sH)[i] = 0u;
    if (l < 4) ((unsigned*)zblk)[l] = 0u;
    __syncthreads();

    const float* WZRH_H = WC;
    const float* WZR_X = WC + 2048;
    const float* WH_H = WC + 2560;
    const float* WH_X = WC + 3584;
    const float* BZR = WC + 3840;
    const float* BH = WC + 3904;

    // weight A'-fragments (held whole run)
    bf16x8 wZRH[4], wZRX[4], wHH[2], wHX[2];
#pragma unroll
    for (int mt = 0; mt < 4; mt++) {
        int j = mt * 16 + lo16;
#pragma unroll
        for (int e = 0; e < 8; e++) {
            wZRH[mt][e] = (short)f2bf(WZRH_H[j * 32 + g * 8 + e]);
            wZRX[mt][e] = (g == 0) ? (short)f2bf(WZR_X[j * 8 + e]) : (short)0;
        }
    }
#pragma unroll
    for (int mt = 0; mt < 2; mt++) {
        int j = mt * 16 + lo16;
#pragma unroll
        for (int e = 0; e < 8; e++) {
            wHH[mt][e] = (short)f2bf(WH_H[j * 32 + g * 8 + e]);
            wHX[mt][e] = (g == 0) ? (short)f2bf(WH_X[j * 8 + e]) : (short)0;
        }
    }

    float bzr[4][4], bhh[2][4], wpr[2][4];
#pragma unroll
    for (int mt = 0; mt < 4; mt++)
#pragma unroll
        for (int r = 0; r < 4; r++) bzr[mt][r] = BZR[mt * 16 + 4 * g + r];
#pragma unroll
    for (int mt = 0; mt < 2; mt++)
#pragma unroll
        for (int r = 0; r < 4; r++) {
            bhh[mt][r] = BH[mt * 16 + 4 * g + r];
            wpr[mt][r] = Wp[mt * 16 + 4 * g + r];
        }

    // softmax(att)
    float am = att[0];
    for (int t = 1; t < 12; t++) am = fmaxf(am, att[t]);
    float ad = 0.0f;
    for (int t = 0; t < 12; t++) ad += __expf(att[t] - am);
    float inv_ad = 1.0f / ad;

    float H[2][4][4], acc[2][4][4];
#pragma unroll
    for (int mt = 0; mt < 2; mt++)
#pragma unroll
        for (int nt = 0; nt < 4; nt++)
#pragma unroll
            for (int r = 0; r < 4; r++) { H[mt][nt][r] = 0.0f; acc[mt][nt][r] = 0.0f; }

    const f32x4 kc = {0.0f, 0.0f, 0.0f, 0.0f};

#pragma unroll 1
    for (int t = 0; t < 12; t++) {
        float pt = __expf(att[t] - am) * inv_ad;

        bf16x8 bH[4], bX[4];
#pragma unroll
        for (int nt = 0; nt < 4; nt++) {
            bH[nt] = *(const bf16x8*)(&sH[(nt * 16 + lo16) * 40 + g * 8]);
            const unsigned short* px = (g == 0) ? &sXp[t * 512 + (nt * 16 + lo16) * 8] : &zblk[0];
            bX[nt] = *(const bf16x8*)px;
        }

        // Z (j' tiles 0,1)
        float Z[2][4][4];
#pragma unroll
        for (int mt = 0; mt < 2; mt++)
#pragma unroll
            for (int nt = 0; nt < 4; nt++) {
                f32x4 d = MFMA_B16(wZRH[mt], bH[nt], kc);
                d = MFMA_B16(wZRX[mt], bX[nt], d);
#pragma unroll
                for (int r = 0; r < 4; r++) Z[mt][nt][r] = sigf(d[r] + bzr[mt][r]);
            }

        // R (tiles 2,3) -> RH, store bf16
#pragma unroll
        for (int mt = 2; mt < 4; mt++)
#pragma unroll
            for (int nt = 0; nt < 4; nt++) {
                f32x4 d = MFMA_B16(wZRH[mt], bH[nt], kc);
                d = MFMA_B16(wZRX[mt], bX[nt], d);
                float rh[4];
#pragma unroll
                for (int r = 0; r < 4; r++)
                    rh[r] = H[mt - 2][nt][r] * sigf(d[r] + bzr[mt][r]);
                uint2 w;
                w.x = (unsigned)f2bf(rh[0]) | ((unsigned)f2bf(rh[1]) << 16);
                w.y = (unsigned)f2bf(rh[2]) | ((unsigned)f2bf(rh[3]) << 16);
                *(uint2*)(&sRH[(nt * 16 + lo16) * 40 + (mt - 2) * 16 + 4 * g]) = w;
            }

        bf16x8 bR[4];
#pragma unroll
        for (int nt = 0; nt < 4; nt++)
            bR[nt] = *(const bf16x8*)(&sRH[(nt * 16 + lo16) * 40 + g * 8]);

        // candidate + update + attention accumulate + H write-back
#pragma unroll
        for (int mt = 0; mt < 2; mt++)
#pragma unroll
            for (int nt = 0; nt < 4; nt++) {
                f32x4 d = MFMA_B16(wHH[mt], bR[nt], kc);
                d = MFMA_B16(wHX[mt], bX[nt], d);
#pragma unroll
                for (int r = 0; r < 4; r++) {
                    float T = tanh_fast(d[r] + bhh[mt][r]);
                    float z = Z[mt][nt][r];
                    float h = T + z * (H[mt][nt][r] - T);
                    H[mt][nt][r] = h;
                    acc[mt][nt][r] += pt * h;
                }
                uint2 w;
                w.x = (unsigned)f2bf(H[mt][nt][0]) | ((unsigned)f2bf(H[mt][nt][1]) << 16);
                w.y = (unsigned)f2bf(H[mt][nt][2]) | ((unsigned)f2bf(H[mt][nt][3]) << 16);
                *(uint2*)(&sH[(nt * 16 + lo16) * 40 + mt * 16 + 4 * g]) = w;
            }
    }

    // epilogue: out[node] = relu( sum_j relu(acc)*Wp + bp + x[node,1,11] )
    float res[4];
#pragma unroll
    for (int nt = 0; nt < 4; nt++) {
        float p = 0.0f;
#pragma unroll
        for (int mt = 0; mt < 2; mt++)
#pragma unroll
            for (int r = 0; r < 4; r++) p += fmaxf(acc[mt][nt][r], 0.0f) * wpr[mt][r];
        p += __shfl_xor(p, 16);
        p += __shfl_xor(p, 32);
        res[nt] = p;
    }
    if (l < 16) {
        float bpv = bp[0];
#pragma unroll
        for (int nt = 0; nt < 4; nt++) {
            int nd = base + nt * 16 + l;
            if (nd < n) out[nd] = fmaxf(res[nt] + bpv + x[(size_t)nd * 96 + 23], 0.0f);
        }
    }
}

// ---------------------------------------------------------------------------
static inline size_t align_up(size_t v, size_t a) { return (v + a - 1) & ~(a - 1); }

extern "C" void kernel_launch(void* const* d_in, const int* in_sizes, int n_in,
                              void* d_out, int out_size, void* d_ws, size_t ws_size,
                              hipStream_t stream) {
    const float* x   = (const float*)d_in[0];
    const int*   ei  = (const int*)d_in[1];
    const float* ew  = (const float*)d_in[2];
    const float* Wz  = (const float*)d_in[3];
    const float* bz  = (const float*)d_in[4];
    const float* Wr  = (const float*)d_in[5];
    const float* br  = (const float*)d_in[6];
    const float* Wh  = (const float*)d_in[7];
    const float* bh  = (const float*)d_in[8];
    const float* Lz  = (const float*)d_in[9];
    const float* lbz = (const float*)d_in[10];
    const float* Lr  = (const float*)d_in[11];
    const float* lbr = (const float*)d_in[12];
    const float* Lh  = (const float*)d_in[13];
    const float* lbh = (const float*)d_in[14];
    const float* att = (const float*)d_in[15];
    const float* Wp  = (const float*)d_in[16];
    const float* bp  = (const float*)d_in[17];
    float* out = (float*)d_out;

    const int N = in_sizes[0] / 96;
    const int E = in_sizes[2];

    char* ws = (char*)d_ws;
    size_t off = 0;
    float* deg    = (float*)(ws + off); off = align_up(off + (size_t)N * 4, 256);
    int*   cnt    = (int*)  (ws + off); off = align_up(off + (size_t)N * 4, 256);
    int*   cursor = (int*)  (ws + off); off = align_up(off + (size_t)N * 4, 256);
    int*   rowptr = (int*)  (ws + off); off = align_up(off + (size_t)(N + 1) * 4, 256);
    int*   csrc   = (int*)  (ws + off); off = align_up(off + (size_t)E * 4, 256);
    float* ccoef  = (float*)(ws + off); off = align_up(off + (size_t)E * 4, 256);
    unsigned short* Xb = (unsigned short*)(ws + off); off = align_up(off + (size_t)N * 96 * 2, 256);
    unsigned short* Xp = (unsigned short*)(ws + off); off = align_up(off + (size_t)N * 96 * 2, 256);
    float* WC     = (float*)(ws + off); off = align_up(off + 3936 * 4, 256);

    hipMemsetAsync(deg, 0, (size_t)N * 4, stream);
    hipMemsetAsync(cnt, 0, (size_t)N * 4, stream);
    hipMemsetAsync(cursor, 0, (size_t)N * 4, stream);

    int eb = (E + 255) / 256;
    int nb = (N + 255) / 256;
    int n96_4 = N * 96 / 4;

    k_cast<<<(n96_4 + 255) / 256, 256, 0, stream>>>(x, Xb, n96_4);
    k_wprep<<<1, 256, 0, stream>>>(Wz, Wr, Wh, Lz, Lr, Lh, bz, br, bh, lbz, lbr, lbh, WC);
    k_edge_pass1<<<eb, 256, 0, stream>>>(ei, ew, deg, cnt, E);
    k_dinv<<<nb, 256, 0, stream>>>(deg, N);
    k_scan<<<1, 1024, 0, stream>>>(cnt, rowptr, N);
    k_fill<<<eb, 256, 0, stream>>>(ei, ew, deg, rowptr, cursor, csrc, ccoef, E);
    k_pull<<<(N * 4 + 255) / 256, 256, 0, stream>>>(Xb, deg, rowptr, csrc, ccoef, Xp, N);
    k_gru<<<(N + 63) / 64, 64, 0, stream>>>(Xp, x, WC, att, Wp, bp, out, N);
}

// Round 3
// 635.017 us; speedup vs baseline: 2.8992x; 1.4086x over previous
//
#include <hip/hip_runtime.h>
#include <cstddef>

typedef __attribute__((ext_vector_type(8))) short bf16x8;
typedef __attribute__((ext_vector_type(4))) float f32x4;

#define MFMA_B16(a, b, c) __builtin_amdgcn_mfma_f32_16x16x32_bf16(a, b, c, 0, 0, 0)

#define DEV_INLINE __device__ __forceinline__

DEV_INLINE float sigf(float x) { return 1.0f / (1.0f + __expf(-x)); }
DEV_INLINE float tanh_fast(float x) { float e2 = __expf(2.0f * x); return 1.0f - 2.0f / (e2 + 1.0f); }

DEV_INLINE unsigned short f2bf(float f) {
    union { float f; unsigned u; } v; v.f = f;
    unsigned r = v.u + 0x7fffu + ((v.u >> 16) & 1u);
    return (unsigned short)(r >> 16);
}
DEV_INLINE float bflo(unsigned w) { union { unsigned u; float f; } t; t.u = w << 16; return t.f; }
DEV_INLINE float bfhi(unsigned w) { union { unsigned u; float f; } t; t.u = w & 0xffff0000u; return t.f; }

// ---------------------------------------------------------------------------
// Cast x (f32, [N][96] in [f][t] order) -> bf16 copy
// ---------------------------------------------------------------------------
__global__ __launch_bounds__(256) void k_cast(const float* __restrict__ x,
                                              unsigned short* __restrict__ Xb, int n96_4) {
    int i = blockIdx.x * 256 + threadIdx.x;
    if (i >= n96_4) return;
    float4 v = *(const float4*)(x + (size_t)i * 4);
    ushort4 o;
    o.x = f2bf(v.x); o.y = f2bf(v.y); o.z = f2bf(v.z); o.w = f2bf(v.w);
    *(ushort4*)(Xb + (size_t)i * 4) = o;
}

// ---------------------------------------------------------------------------
// Edge pass 1: ONE packed 64-bit atomic per edge.
//   pk[d] += (1 << 40) | round(w * 2^20)
// Returned old value gives this edge's rank within its dst row (old >> 40).
// ---------------------------------------------------------------------------
__global__ __launch_bounds__(256) void k_edge_pass1(const int* __restrict__ ei,
                                                    const float* __restrict__ ew,
                                                    unsigned long long* __restrict__ pk,
                                                    unsigned short* __restrict__ rank, int E) {
    int e = blockIdx.x * 256 + threadIdx.x;
    if (e >= E) return;
    int d = ei[(size_t)E + e];
    float w = ew[e];
    unsigned long long add = (1ull << 40) | (unsigned long long)(unsigned)(w * 1048576.0f + 0.5f);
    unsigned long long old = atomicAdd(pk + d, add);
    rank[e] = (unsigned short)(old >> 40);
}

// unpack: dinv[i] = rsqrt(deg+1), cnt[i] = count
__global__ __launch_bounds__(256) void k_dinv(const unsigned long long* __restrict__ pk,
                                              float* __restrict__ dinv,
                                              int* __restrict__ cnt, int n) {
    int i = blockIdx.x * 256 + threadIdx.x;
    if (i >= n) return;
    unsigned long long p = pk[i];
    float deg = (float)(p & ((1ull << 40) - 1)) * (1.0f / 1048576.0f);
    dinv[i] = rsqrtf(deg + 1.0f);
    cnt[i] = (int)(p >> 40);
}

// ---------------------------------------------------------------------------
// Exclusive scan (single block)
// ---------------------------------------------------------------------------
__global__ __launch_bounds__(1024) void k_scan(const int* __restrict__ cnt,
                                               int* __restrict__ rowptr, int n) {
    __shared__ int sums[1024];
    int t = threadIdx.x;
    int chunk = (n + 1023) >> 10;
    int lo = t * chunk;
    int hi = min(lo + chunk, n);
    int s = 0;
    for (int i = lo; i < hi; i++) s += cnt[i];
    sums[t] = s;
    __syncthreads();
    for (int off = 1; off < 1024; off <<= 1) {
        int v = sums[t];
        int w = (t >= off) ? sums[t - off] : 0;
        __syncthreads();
        sums[t] = v + w;
        __syncthreads();
    }
    int run = (t > 0) ? sums[t - 1] : 0;
    for (int i = lo; i < hi; i++) { rowptr[i] = run; run += cnt[i]; }
    if (lo < n && hi == n) rowptr[n] = run;
}

// ---------------------------------------------------------------------------
// Fill CSR by dst — atomic-free: position = rowptr[d] + rank[e].
// cedge[p] = { src, coef_bits } interleaved.
// ---------------------------------------------------------------------------
__global__ __launch_bounds__(256) void k_fill(const int* __restrict__ ei,
                                              const float* __restrict__ ew,
                                              const float* __restrict__ dinv,
                                              const int* __restrict__ rowptr,
                                              const unsigned short* __restrict__ rank,
                                              uint2* __restrict__ cedge, int E) {
    int e = blockIdx.x * 256 + threadIdx.x;
    if (e >= E) return;
    int s = ei[e];
    int d = ei[(size_t)E + e];
    float cf = dinv[s] * ew[e] * dinv[d];
    int p = rowptr[d] + (int)rank[e];
    uint2 v;
    v.x = (unsigned)s;
    v.y = __float_as_uint(cf);
    cedge[p] = v;
}

// ---------------------------------------------------------------------------
// Pull aggregation in bf16. 4 threads/node; thread c owns features f=2c,2c+1
// (elements [c*24, c*24+24) of the [f][t] row). Output Xp is bf16 in
// [node][t*8+f] order (GRU staging layout).
// ---------------------------------------------------------------------------
__global__ __launch_bounds__(256) void k_pull(const unsigned short* __restrict__ Xb,
                                              const float* __restrict__ dinv,
                                              const int* __restrict__ rowptr,
                                              const uint2* __restrict__ cedge,
                                              unsigned short* __restrict__ Xp, int n) {
    int gid = blockIdx.x * 256 + threadIdx.x;
    int d = gid >> 2;
    int c = gid & 3;
    if (d >= n) return;
    float di = dinv[d];
    float sl = di * di;
    float a[24];
    {
        const unsigned short* xr = Xb + (size_t)d * 96 + c * 24;
#pragma unroll
        for (int q = 0; q < 3; q++) {
            uint4 v = *(const uint4*)(xr + q * 8);
            a[q * 8 + 0] = sl * bflo(v.x); a[q * 8 + 1] = sl * bfhi(v.x);
            a[q * 8 + 2] = sl * bflo(v.y); a[q * 8 + 3] = sl * bfhi(v.y);
            a[q * 8 + 4] = sl * bflo(v.z); a[q * 8 + 5] = sl * bfhi(v.z);
            a[q * 8 + 6] = sl * bflo(v.w); a[q * 8 + 7] = sl * bfhi(v.w);
        }
    }
    int lo = rowptr[d], hi = rowptr[d + 1];
    for (int e = lo; e < hi; e++) {
        uint2 se = cedge[e];
        int s = (int)se.x;
        float cf = __uint_as_float(se.y);
        const unsigned short* xs = Xb + (size_t)s * 96 + c * 24;
#pragma unroll
        for (int q = 0; q < 3; q++) {
            uint4 v = *(const uint4*)(xs + q * 8);
            a[q * 8 + 0] += cf * bflo(v.x); a[q * 8 + 1] += cf * bfhi(v.x);
            a[q * 8 + 2] += cf * bflo(v.y); a[q * 8 + 3] += cf * bfhi(v.y);
            a[q * 8 + 4] += cf * bflo(v.z); a[q * 8 + 5] += cf * bfhi(v.z);
            a[q * 8 + 6] += cf * bflo(v.w); a[q * 8 + 7] += cf * bfhi(v.w);
        }
    }
    // a[0..11]: f=2c, t=0..11 ; a[12..23]: f=2c+1
    unsigned short* o = Xp + (size_t)d * 96;
#pragma unroll
    for (int t = 0; t < 12; t++) {
        unsigned w = (unsigned)f2bf(a[t]) | ((unsigned)f2bf(a[12 + t]) << 16);
        *(unsigned*)(o + t * 8 + 2 * c) = w;
    }
}

// ---------------------------------------------------------------------------
// Weight precompute: fold input matvec into gate GEMM (swapped layout).
// WC layout (floats):
//   [0,2048)    WZRH_H[64][32] : row j' (0..31 Z, 32..63 R), col k: L{z|r}[32+k][j'&31]
//   [2048,2560) WZR_X [64][8]  : (W{z|r} @ L{z|r}_top)[f][j'&31]
//   [2560,3584) WH_H  [32][32] : Lh[32+k][j]
//   [3584,3840) WH_X  [32][8]  : (Wh @ Lh_top)[f][j]
//   [3840,3904) BZR[64] = b@L_top + lb
//   [3904,3936) BH[32]
// ---------------------------------------------------------------------------
__global__ __launch_bounds__(256) void k_wprep(const float* __restrict__ Wz, const float* __restrict__ Wr,
                                               const float* __restrict__ Wh,
                                               const float* __restrict__ Lz, const float* __restrict__ Lr,
                                               const float* __restrict__ Lh,
                                               const float* __restrict__ bz, const float* __restrict__ br,
                                               const float* __restrict__ bh,
                                               const float* __restrict__ lbz, const float* __restrict__ lbr,
                                               const float* __restrict__ lbh,
                                               float* __restrict__ WC) {
    int tid = threadIdx.x;
    for (int e = tid; e < 2048; e += 256) {
        int j = e >> 5, k = e & 31;
        const float* L = (j < 32) ? Lz : Lr;
        WC[e] = L[(32 + k) * 32 + (j & 31)];
    }
    for (int e = tid; e < 512; e += 256) {
        int j = e >> 3, f = e & 7;
        const float* L = (j < 32) ? Lz : Lr;
        const float* W = (j < 32) ? Wz : Wr;
        int jj = j & 31;
        float s = 0.0f;
        for (int i = 0; i < 32; i++) s += W[f * 32 + i] * L[i * 32 + jj];
        WC[2048 + e] = s;
    }
    for (int e = tid; e < 1024; e += 256) {
        int j = e >> 5, k = e & 31;
        WC[2560 + e] = Lh[(32 + k) * 32 + j];
    }
    for (int e = tid; e < 256; e += 256) {
        int j = e >> 3, f = e & 7;
        float s = 0.0f;
        for (int i = 0; i < 32; i++) s += Wh[f * 32 + i] * Lh[i * 32 + j];
        WC[3584 + e] = s;
    }
    if (tid < 64) {
        int j = tid;
        const float* L = (j < 32) ? Lz : Lr;
        const float* b = (j < 32) ? bz : br;
        const float* lb = (j < 32) ? lbz : lbr;
        int jj = j & 31;
        float s = lb[jj];
        for (int i = 0; i < 32; i++) s += b[i] * L[i * 32 + jj];
        WC[3840 + j] = s;
    }
    if (tid < 32) {
        float s = lbh[tid];
        for (int i = 0; i < 32; i++) s += bh[i] * Lh[i * 32 + tid];
        WC[3904 + tid] = s;
    }
}

// ---------------------------------------------------------------------------
// MFMA GRU: one wave (64 threads) per 64-node tile. Swapped GEMM:
//   D[j'][node] = sum_k A'[j'][k] * B'[k][node]
// A' = weights (loaded once to frags), B' = [H | Xt] from per-wave LDS.
// D layout: node = lane&15 (+16*nt), j' = 16*mt + 4*(lane>>4) + r.
// H state kept f32 in D-layout regs; bf16 copy in sH (stride 40) for B-frags.
// ---------------------------------------------------------------------------
__global__ __launch_bounds__(64, 2) void k_gru(const unsigned short* __restrict__ Xp,
                                               const float* __restrict__ x,
                                               const float* __restrict__ WC,
                                               const float* __restrict__ att,
                                               const float* __restrict__ Wp,
                                               const float* __restrict__ bp,
                                               float* __restrict__ out, int n) {
    __shared__ __align__(16) unsigned short sH[64 * 40];
    __shared__ __align__(16) unsigned short sRH[64 * 40];
    __shared__ __align__(16) unsigned short sXp[12 * 64 * 8];
    __shared__ __align__(16) unsigned short zblk[8];

    const int l = threadIdx.x;
    const int lo16 = l & 15;
    const int g = l >> 4;
    const int base = blockIdx.x * 64;
    const int cnode = min(base + l, n - 1);

    // stage this wave's Xp rows: chunk q of a row == (t=q, f=0..7)
    {
        const unsigned short* xrow = Xp + (size_t)cnode * 96;
#pragma unroll
        for (int q = 0; q < 12; q++) {
            uint4 v = *(const uint4*)(xrow + q * 8);
            *(uint4*)(&sXp[q * 512 + l * 8]) = v;
        }
    }
    // zero H tile + zero block
    for (int i = l; i < 64 * 40 / 2; i += 64) ((unsigned*)sH)[i] = 0u;
    if (l < 4) ((unsigned*)zblk)[l] = 0u;
    __syncthreads();

    const float* WZRH_H = WC;
    const float* WZR_X = WC + 2048;
    const float* WH_H = WC + 2560;
    const float* WH_X = WC + 3584;
    const float* BZR = WC + 3840;
    const float* BH = WC + 3904;

    // weight A'-fragments (held whole run)
    bf16x8 wZRH[4], wZRX[4], wHH[2], wHX[2];
#pragma unroll
    for (int mt = 0; mt < 4; mt++) {
        int j = mt * 16 + lo16;
#pragma unroll
        for (int e = 0; e < 8; e++) {
            wZRH[mt][e] = (short)f2bf(WZRH_H[j * 32 + g * 8 + e]);
            wZRX[mt][e] = (g == 0) ? (short)f2bf(WZR_X[j * 8 + e]) : (short)0;
        }
    }
#pragma unroll
    for (int mt = 0; mt < 2; mt++) {
        int j = mt * 16 + lo16;
#pragma unroll
        for (int e = 0; e < 8; e++) {
            wHH[mt][e] = (short)f2bf(WH_H[j * 32 + g * 8 + e]);
            wHX[mt][e] = (g == 0) ? (short)f2bf(WH_X[j * 8 + e]) : (short)0;
        }
    }

    float bzr[4][4], bhh[2][4], wpr[2][4];
#pragma unroll
    for (int mt = 0; mt < 4; mt++)
#pragma unroll
        for (int r = 0; r < 4; r++) bzr[mt][r] = BZR[mt * 16 + 4 * g + r];
#pragma unroll
    for (int mt = 0; mt < 2; mt++)
#pragma unroll
        for (int r = 0; r < 4; r++) {
            bhh[mt][r] = BH[mt * 16 + 4 * g + r];
            wpr[mt][r] = Wp[mt * 16 + 4 * g + r];
        }

    // softmax(att)
    float am = att[0];
    for (int t = 1; t < 12; t++) am = fmaxf(am, att[t]);
    float ad = 0.0f;
    for (int t = 0; t < 12; t++) ad += __expf(att[t] - am);
    float inv_ad = 1.0f / ad;

    float H[2][4][4], acc[2][4][4];
#pragma unroll
    for (int mt = 0; mt < 2; mt++)
#pragma unroll
        for (int nt = 0; nt < 4; nt++)
#pragma unroll
            for (int r = 0; r < 4; r++) { H[mt][nt][r] = 0.0f; acc[mt][nt][r] = 0.0f; }

    const f32x4 kc = {0.0f, 0.0f, 0.0f, 0.0f};

#pragma unroll 1
    for (int t = 0; t < 12; t++) {
        float pt = __expf(att[t] - am) * inv_ad;

        bf16x8 bH[4], bX[4];
#pragma unroll
        for (int nt = 0; nt < 4; nt++) {
            bH[nt] = *(const bf16x8*)(&sH[(nt * 16 + lo16) * 40 + g * 8]);
            const unsigned short* px = (g == 0) ? &sXp[t * 512 + (nt * 16 + lo16) * 8] : &zblk[0];
            bX[nt] = *(const bf16x8*)px;
        }

        // Z (j' tiles 0,1)
        float Z[2][4][4];
#pragma unroll
        for (int mt = 0; mt < 2; mt++)
#pragma unroll
            for (int nt = 0; nt < 4; nt++) {
                f32x4 d = MFMA_B16(wZRH[mt], bH[nt], kc);
                d = MFMA_B16(wZRX[mt], bX[nt], d);
#pragma unroll
                for (int r = 0; r < 4; r++) Z[mt][nt][r] = sigf(d[r] + bzr[mt][r]);
            }

        // R (tiles 2,3) -> RH, store bf16
#pragma unroll
        for (int mt = 2; mt < 4; mt++)
#pragma unroll
            for (int nt = 0; nt < 4; nt++) {
                f32x4 d = MFMA_B16(wZRH[mt], bH[nt], kc);
                d = MFMA_B16(wZRX[mt], bX[nt], d);
                float rh[4];
#pragma unroll
                for (int r = 0; r < 4; r++)
                    rh[r] = H[mt - 2][nt][r] * sigf(d[r] + bzr[mt][r]);
                uint2 w;
                w.x = (unsigned)f2bf(rh[0]) | ((unsigned)f2bf(rh[1]) << 16);
                w.y = (unsigned)f2bf(rh[2]) | ((unsigned)f2bf(rh[3]) << 16);
                *(uint2*)(&sRH[(nt * 16 + lo16) * 40 + (mt - 2) * 16 + 4 * g]) = w;
            }

        bf16x8 bR[4];
#pragma unroll
        for (int nt = 0; nt < 4; nt++)
            bR[nt] = *(const bf16x8*)(&sRH[(nt * 16 + lo16) * 40 + g * 8]);

        // candidate + update + attention accumulate + H write-back
#pragma unroll
        for (int mt = 0; mt < 2; mt++)
#pragma unroll
            for (int nt = 0; nt < 4; nt++) {
                f32x4 d = MFMA_B16(wHH[mt], bR[nt], kc);
                d = MFMA_B16(wHX[mt], bX[nt], d);
#pragma unroll
                for (int r = 0; r < 4; r++) {
                    float T = tanh_fast(d[r] + bhh[mt][r]);
                    float z = Z[mt][nt][r];
                    float h = T + z * (H[mt][nt][r] - T);
                    H[mt][nt][r] = h;
                    acc[mt][nt][r] += pt * h;
                }
                uint2 w;
                w.x = (unsigned)f2bf(H[mt][nt][0]) | ((unsigned)f2bf(H[mt][nt][1]) << 16);
                w.y = (unsigned)f2bf(H[mt][nt][2]) | ((unsigned)f2bf(H[mt][nt][3]) << 16);
                *(uint2*)(&sH[(nt * 16 + lo16) * 40 + mt * 16 + 4 * g]) = w;
            }
    }

    // epilogue: out[node] = relu( sum_j relu(acc)*Wp + bp + x[node,1,11] )
    float res[4];
#pragma unroll
    for (int nt = 0; nt < 4; nt++) {
        float p = 0.0f;
#pragma unroll
        for (int mt = 0; mt < 2; mt++)
#pragma unroll
            for (int r = 0; r < 4; r++) p += fmaxf(acc[mt][nt][r], 0.0f) * wpr[mt][r];
        p += __shfl_xor(p, 16);
        p += __shfl_xor(p, 32);
        res[nt] = p;
    }
    if (l < 16) {
        float bpv = bp[0];
#pragma unroll
        for (int nt = 0; nt < 4; nt++) {
            int nd = base + nt * 16 + l;
            if (nd < n) out[nd] = fmaxf(res[nt] + bpv + x[(size_t)nd * 96 + 23], 0.0f);
        }
    }
}

// ---------------------------------------------------------------------------
static inline size_t align_up(size_t v, size_t a) { return (v + a - 1) & ~(a - 1); }

extern "C" void kernel_launch(void* const* d_in, const int* in_sizes, int n_in,
                              void* d_out, int out_size, void* d_ws, size_t ws_size,
                              hipStream_t stream) {
    const float* x   = (const float*)d_in[0];
    const int*   ei  = (const int*)d_in[1];
    const float* ew  = (const float*)d_in[2];
    const float* Wz  = (const float*)d_in[3];
    const float* bz  = (const float*)d_in[4];
    const float* Wr  = (const float*)d_in[5];
    const float* br  = (const float*)d_in[6];
    const float* Wh  = (const float*)d_in[7];
    const float* bh  = (const float*)d_in[8];
    const float* Lz  = (const float*)d_in[9];
    const float* lbz = (const float*)d_in[10];
    const float* Lr  = (const float*)d_in[11];
    const float* lbr = (const float*)d_in[12];
    const float* Lh  = (const float*)d_in[13];
    const float* lbh = (const float*)d_in[14];
    const float* att = (const float*)d_in[15];
    const float* Wp  = (const float*)d_in[16];
    const float* bp  = (const float*)d_in[17];
    float* out = (float*)d_out;

    const int N = in_sizes[0] / 96;
    const int E = in_sizes[2];

    char* ws = (char*)d_ws;
    size_t off = 0;
    unsigned long long* pk = (unsigned long long*)(ws + off); off = align_up(off + (size_t)N * 8, 256);
    float* dinv   = (float*)(ws + off); off = align_up(off + (size_t)N * 4, 256);
    int*   cnt    = (int*)  (ws + off); off = align_up(off + (size_t)N * 4, 256);
    int*   rowptr = (int*)  (ws + off); off = align_up(off + (size_t)(N + 1) * 4, 256);
    uint2* cedge  = (uint2*)(ws + off); off = align_up(off + (size_t)E * 8, 256);
    unsigned short* Xb = (unsigned short*)(ws + off); off = align_up(off + (size_t)N * 96 * 2, 256);
    unsigned short* Xp = (unsigned short*)(ws + off); off = align_up(off + (size_t)N * 96 * 2, 256);
    float* WC     = (float*)(ws + off); off = align_up(off + 3936 * 4, 256);

    // rank[] overlays the Xp region: written by k_edge_pass1, consumed by
    // k_fill, both strictly before k_pull writes Xp (stream-ordered).
    unsigned short* rank = Xp;

    hipMemsetAsync(pk, 0, (size_t)N * 8, stream);

    int eb = (E + 255) / 256;
    int nb = (N + 255) / 256;
    int n96_4 = N * 96 / 4;

    k_cast<<<(n96_4 + 255) / 256, 256, 0, stream>>>(x, Xb, n96_4);
    k_wprep<<<1, 256, 0, stream>>>(Wz, Wr, Wh, Lz, Lr, Lh, bz, br, bh, lbz, lbr, lbh, WC);
    k_edge_pass1<<<eb, 256, 0, stream>>>(ei, ew, pk, rank, E);
    k_dinv<<<nb, 256, 0, stream>>>(pk, dinv, cnt, N);
    k_scan<<<1, 1024, 0, stream>>>(cnt, rowptr, N);
    k_fill<<<eb, 256, 0, stream>>>(ei, ew, dinv, rowptr, rank, cedge, E);
    k_pull<<<(N * 4 + 255) / 256, 256, 0, stream>>>(Xb, dinv, rowptr, cedge, Xp, N);
    k_gru<<<(N + 63) / 64, 64, 0, stream>>>(Xp, x, WC, att, Wp, bp, out, N);
}

// Round 4
// 481.081 us; speedup vs baseline: 3.8269x; 1.3200x over previous
//
#include <hip/hip_runtime.h>
#include <cstddef>

typedef __attribute__((ext_vector_type(8))) short bf16x8;
typedef __attribute__((ext_vector_type(4))) float f32x4;

#define MFMA_B16(a, b, c) __builtin_amdgcn_mfma_f32_16x16x32_bf16(a, b, c, 0, 0, 0)

#define DEV_INLINE __device__ __forceinline__

DEV_INLINE float sigf(float x) { return 1.0f / (1.0f + __expf(-x)); }
DEV_INLINE float tanh_fast(float x) { float e2 = __expf(2.0f * x); return 1.0f - 2.0f / (e2 + 1.0f); }

DEV_INLINE unsigned short f2bf(float f) {
    union { float f; unsigned u; } v; v.f = f;
    unsigned r = v.u + 0x7fffu + ((v.u >> 16) & 1u);
    return (unsigned short)(r >> 16);
}
DEV_INLINE float bflo(unsigned w) { union { unsigned u; float f; } t; t.u = w << 16; return t.f; }
DEV_INLINE float bfhi(unsigned w) { union { unsigned u; float f; } t; t.u = w & 0xffff0000u; return t.f; }

// ---------------------------------------------------------------------------
// Cast x (f32, [N][96] in [f][t] order) -> bf16 copy
// ---------------------------------------------------------------------------
__global__ __launch_bounds__(256) void k_cast(const float* __restrict__ x,
                                              unsigned short* __restrict__ Xb, int n96_4) {
    int i = blockIdx.x * 256 + threadIdx.x;
    if (i >= n96_4) return;
    float4 v = *(const float4*)(x + (size_t)i * 4);
    ushort4 o;
    o.x = f2bf(v.x); o.y = f2bf(v.y); o.z = f2bf(v.z); o.w = f2bf(v.w);
    *(ushort4*)(Xb + (size_t)i * 4) = o;
}

// ---------------------------------------------------------------------------
// Edge pass 1: ONE packed 64-bit atomic per edge.
//   pk[d] += (1 << 40) | round(w * 2^20)
// Returned old value gives this edge's rank within its dst row (old >> 40).
// ---------------------------------------------------------------------------
__global__ __launch_bounds__(256) void k_edge_pass1(const int* __restrict__ ei,
                                                    const float* __restrict__ ew,
                                                    unsigned long long* __restrict__ pk,
                                                    unsigned short* __restrict__ rank, int E) {
    int e = blockIdx.x * 256 + threadIdx.x;
    if (e >= E) return;
    int d = ei[(size_t)E + e];
    float w = ew[e];
    unsigned long long add = (1ull << 40) | (unsigned long long)(unsigned)(w * 1048576.0f + 0.5f);
    unsigned long long old = atomicAdd(pk + d, add);
    rank[e] = (unsigned short)(old >> 40);
}

// ---------------------------------------------------------------------------
// Scan phase 1: per-block (2048 elems) local exclusive scan of counts,
// fused with dinv unpack. rowptr gets LOCAL prefixes; bsum gets block totals.
// ---------------------------------------------------------------------------
__global__ __launch_bounds__(256) void k_scan1(const unsigned long long* __restrict__ pk,
                                               float* __restrict__ dinv,
                                               int* __restrict__ rowptr,
                                               int* __restrict__ bsum, int n) {
    __shared__ int ts[256];
    const int t = threadIdx.x;
    const int i0 = blockIdx.x * 2048 + t * 8;

    unsigned long long p[8];
    int c[8];
    float dv[8];
    if (i0 + 8 <= n) {
#pragma unroll
        for (int q = 0; q < 8; q++) p[q] = pk[i0 + q];
    } else {
#pragma unroll
        for (int q = 0; q < 8; q++) p[q] = (i0 + q < n) ? pk[i0 + q] : 0ull;
    }
    int s = 0;
#pragma unroll
    for (int q = 0; q < 8; q++) {
        c[q] = (int)(p[q] >> 40);
        float deg = (float)(p[q] & ((1ull << 40) - 1)) * (1.0f / 1048576.0f);
        dv[q] = rsqrtf(deg + 1.0f);
        s += c[q];
    }
    ts[t] = s;
    __syncthreads();
    for (int off = 1; off < 256; off <<= 1) {
        int v = ts[t];
        int w = (t >= off) ? ts[t - off] : 0;
        __syncthreads();
        ts[t] = v + w;
        __syncthreads();
    }
    int run = (t > 0) ? ts[t - 1] : 0;

    if (i0 + 8 <= n) {
        float4 d0 = {dv[0], dv[1], dv[2], dv[3]};
        float4 d1 = {dv[4], dv[5], dv[6], dv[7]};
        *(float4*)(dinv + i0) = d0;
        *(float4*)(dinv + i0 + 4) = d1;
        int r[8];
#pragma unroll
        for (int q = 0; q < 8; q++) { r[q] = run; run += c[q]; }
        *(int4*)(rowptr + i0) = *(int4*)r;
        *(int4*)(rowptr + i0 + 4) = *(int4*)(r + 4);
    } else {
        for (int q = 0; q < 8; q++) {
            if (i0 + q < n) { dinv[i0 + q] = dv[q]; rowptr[i0 + q] = run; }
            run += c[q];
        }
    }
    if (t == 255) bsum[blockIdx.x] = ts[255];
}

// ---------------------------------------------------------------------------
// Scan phase 2: exclusive scan of block sums (nb <= 256, i.e. N <= 524288)
// ---------------------------------------------------------------------------
__global__ __launch_bounds__(256) void k_scan2(const int* __restrict__ bsum,
                                               int* __restrict__ boff, int nb) {
    __shared__ int ts[256];
    int t = threadIdx.x;
    ts[t] = (t < nb) ? bsum[t] : 0;
    __syncthreads();
    for (int off = 1; off < 256; off <<= 1) {
        int v = ts[t];
        int w = (t >= off) ? ts[t - off] : 0;
        __syncthreads();
        ts[t] = v + w;
        __syncthreads();
    }
    if (t < nb) boff[t] = (t > 0) ? ts[t - 1] : 0;
}

// ---------------------------------------------------------------------------
// Scan phase 3: add block offsets; write rowptr[n] = E.
// ---------------------------------------------------------------------------
__global__ __launch_bounds__(256) void k_scan3(int* __restrict__ rowptr,
                                               const int* __restrict__ boff,
                                               int n, int E) {
    int i = (blockIdx.x * 256 + threadIdx.x) * 4;
    if (i + 4 <= n) {
        int o = boff[i >> 11];
        int4 v = *(int4*)(rowptr + i);
        v.x += o; v.y += o; v.z += o; v.w += o;
        *(int4*)(rowptr + i) = v;
    } else if (i < n) {
        int o = boff[i >> 11];
        for (int q = 0; q < 4 && i + q < n; q++) rowptr[i + q] += o;
    }
    if (i == 0) rowptr[n] = E;
}

// ---------------------------------------------------------------------------
// Fill CSR by dst — atomic-free: position = rowptr[d] + rank[e].
// cedge[p] = { src, coef_bits } interleaved.
// ---------------------------------------------------------------------------
__global__ __launch_bounds__(256) void k_fill(const int* __restrict__ ei,
                                              const float* __restrict__ ew,
                                              const float* __restrict__ dinv,
                                              const int* __restrict__ rowptr,
                                              const unsigned short* __restrict__ rank,
                                              uint2* __restrict__ cedge, int E) {
    int e = blockIdx.x * 256 + threadIdx.x;
    if (e >= E) return;
    int s = ei[e];
    int d = ei[(size_t)E + e];
    float cf = dinv[s] * ew[e] * dinv[d];
    int p = rowptr[d] + (int)rank[e];
    uint2 v;
    v.x = (unsigned)s;
    v.y = __float_as_uint(cf);
    cedge[p] = v;
}

// ---------------------------------------------------------------------------
// Pull aggregation in bf16. 4 threads/node; thread c owns features f=2c,2c+1
// (elements [c*24, c*24+24) of the [f][t] row). Output Xp is bf16 in
// [node][t*8+f] order (GRU staging layout).
// ---------------------------------------------------------------------------
__global__ __launch_bounds__(256) void k_pull(const unsigned short* __restrict__ Xb,
                                              const float* __restrict__ dinv,
                                              const int* __restrict__ rowptr,
                                              const uint2* __restrict__ cedge,
                                              unsigned short* __restrict__ Xp, int n) {
    int gid = blockIdx.x * 256 + threadIdx.x;
    int d = gid >> 2;
    int c = gid & 3;
    if (d >= n) return;
    float di = dinv[d];
    float sl = di * di;
    float a[24];
    {
        const unsigned short* xr = Xb + (size_t)d * 96 + c * 24;
#pragma unroll
        for (int q = 0; q < 3; q++) {
            uint4 v = *(const uint4*)(xr + q * 8);
            a[q * 8 + 0] = sl * bflo(v.x); a[q * 8 + 1] = sl * bfhi(v.x);
            a[q * 8 + 2] = sl * bflo(v.y); a[q * 8 + 3] = sl * bfhi(v.y);
            a[q * 8 + 4] = sl * bflo(v.z); a[q * 8 + 5] = sl * bfhi(v.z);
            a[q * 8 + 6] = sl * bflo(v.w); a[q * 8 + 7] = sl * bfhi(v.w);
        }
    }
    int lo = rowptr[d], hi = rowptr[d + 1];
    for (int e = lo; e < hi; e++) {
        uint2 se = cedge[e];
        int s = (int)se.x;
        float cf = __uint_as_float(se.y);
        const unsigned short* xs = Xb + (size_t)s * 96 + c * 24;
#pragma unroll
        for (int q = 0; q < 3; q++) {
            uint4 v = *(const uint4*)(xs + q * 8);
            a[q * 8 + 0] += cf * bflo(v.x); a[q * 8 + 1] += cf * bfhi(v.x);
            a[q * 8 + 2] += cf * bflo(v.y); a[q * 8 + 3] += cf * bfhi(v.y);
            a[q * 8 + 4] += cf * bflo(v.z); a[q * 8 + 5] += cf * bfhi(v.z);
            a[q * 8 + 6] += cf * bflo(v.w); a[q * 8 + 7] += cf * bfhi(v.w);
        }
    }
    // a[0..11]: f=2c, t=0..11 ; a[12..23]: f=2c+1
    unsigned short* o = Xp + (size_t)d * 96;
#pragma unroll
    for (int t = 0; t < 12; t++) {
        unsigned w = (unsigned)f2bf(a[t]) | ((unsigned)f2bf(a[12 + t]) << 16);
        *(unsigned*)(o + t * 8 + 2 * c) = w;
    }
}

// ---------------------------------------------------------------------------
// Weight precompute: fold input matvec into gate GEMM (swapped layout).
// WC layout (floats):
//   [0,2048)    WZRH_H[64][32] : row j' (0..31 Z, 32..63 R), col k: L{z|r}[32+k][j'&31]
//   [2048,2560) WZR_X [64][8]  : (W{z|r} @ L{z|r}_top)[f][j'&31]
//   [2560,3584) WH_H  [32][32] : Lh[32+k][j]
//   [3584,3840) WH_X  [32][8]  : (Wh @ Lh_top)[f][j]
//   [3840,3904) BZR[64] = b@L_top + lb
//   [3904,3936) BH[32]
// ---------------------------------------------------------------------------
__global__ __launch_bounds__(256) void k_wprep(const float* __restrict__ Wz, const float* __restrict__ Wr,
                                               const float* __restrict__ Wh,
                                               const float* __restrict__ Lz, const float* __restrict__ Lr,
                                               const float* __restrict__ Lh,
                                               const float* __restrict__ bz, const float* __restrict__ br,
                                               const float* __restrict__ bh,
                                               const float* __restrict__ lbz, const float* __restrict__ lbr,
                                               const float* __restrict__ lbh,
                                               float* __restrict__ WC) {
    int tid = threadIdx.x;
    for (int e = tid; e < 2048; e += 256) {
        int j = e >> 5, k = e & 31;
        const float* L = (j < 32) ? Lz : Lr;
        WC[e] = L[(32 + k) * 32 + (j & 31)];
    }
    for (int e = tid; e < 512; e += 256) {
        int j = e >> 3, f = e & 7;
        const float* L = (j < 32) ? Lz : Lr;
        const float* W = (j < 32) ? Wz : Wr;
        int jj = j & 31;
        float s = 0.0f;
        for (int i = 0; i < 32; i++) s += W[f * 32 + i] * L[i * 32 + jj];
        WC[2048 + e] = s;
    }
    for (int e = tid; e < 1024; e += 256) {
        int j = e >> 5, k = e & 31;
        WC[2560 + e] = Lh[(32 + k) * 32 + j];
    }
    for (int e = tid; e < 256; e += 256) {
        int j = e >> 3, f = e & 7;
        float s = 0.0f;
        for (int i = 0; i < 32; i++) s += Wh[f * 32 + i] * Lh[i * 32 + j];
        WC[3584 + e] = s;
    }
    if (tid < 64) {
        int j = tid;
        const float* L = (j < 32) ? Lz : Lr;
        const float* b = (j < 32) ? bz : br;
        const float* lb = (j < 32) ? lbz : lbr;
        int jj = j & 31;
        float s = lb[jj];
        for (int i = 0; i < 32; i++) s += b[i] * L[i * 32 + jj];
        WC[3840 + j] = s;
    }
    if (tid < 32) {
        float s = lbh[tid];
        for (int i = 0; i < 32; i++) s += bh[i] * Lh[i * 32 + tid];
        WC[3904 + tid] = s;
    }
}

// ---------------------------------------------------------------------------
// MFMA GRU: one wave (64 threads) per 64-node tile. Swapped GEMM:
//   D[j'][node] = sum_k A'[j'][k] * B'[k][node]
// A' = weights (loaded once to frags), B' = [H | Xt] from per-wave LDS.
// D layout: node = lane&15 (+16*nt), j' = 16*mt + 4*(lane>>4) + r.
// H state kept f32 in D-layout regs; bf16 copy in sH (stride 40) for B-frags.
// ---------------------------------------------------------------------------
__global__ __launch_bounds__(64, 2) void k_gru(const unsigned short* __restrict__ Xp,
                                               const float* __restrict__ x,
                                               const float* __restrict__ WC,
                                               const float* __restrict__ att,
                                               const float* __restrict__ Wp,
                                               const float* __restrict__ bp,
                                               float* __restrict__ out, int n) {
    __shared__ __align__(16) unsigned short sH[64 * 40];
    __shared__ __align__(16) unsigned short sRH[64 * 40];
    __shared__ __align__(16) unsigned short sXp[12 * 64 * 8];
    __shared__ __align__(16) unsigned short zblk[8];

    const int l = threadIdx.x;
    const int lo16 = l & 15;
    const int g = l >> 4;
    const int base = blockIdx.x * 64;
    const int cnode = min(base + l, n - 1);

    // stage this wave's Xp rows: chunk q of a row == (t=q, f=0..7)
    {
        const unsigned short* xrow = Xp + (size_t)cnode * 96;
#pragma unroll
        for (int q = 0; q < 12; q++) {
            uint4 v = *(const uint4*)(xrow + q * 8);
            *(uint4*)(&sXp[q * 512 + l * 8]) = v;
        }
    }
    // zero H tile + zero block
    for (int i = l; i < 64 * 40 / 2; i += 64) ((unsigned*)sH)[i] = 0u;
    if (l < 4) ((unsigned*)zblk)[l] = 0u;
    __syncthreads();

    const float* WZRH_H = WC;
    const float* WZR_X = WC + 2048;
    const float* WH_H = WC + 2560;
    const float* WH_X = WC + 3584;
    const float* BZR = WC + 3840;
    const float* BH = WC + 3904;

    // weight A'-fragments (held whole run)
    bf16x8 wZRH[4], wZRX[4], wHH[2], wHX[2];
#pragma unroll
    for (int mt = 0; mt < 4; mt++) {
        int j = mt * 16 + lo16;
#pragma unroll
        for (int e = 0; e < 8; e++) {
            wZRH[mt][e] = (short)f2bf(WZRH_H[j * 32 + g * 8 + e]);
            wZRX[mt][e] = (g == 0) ? (short)f2bf(WZR_X[j * 8 + e]) : (short)0;
        }
    }
#pragma unroll
    for (int mt = 0; mt < 2; mt++) {
        int j = mt * 16 + lo16;
#pragma unroll
        for (int e = 0; e < 8; e++) {
            wHH[mt][e] = (short)f2bf(WH_H[j * 32 + g * 8 + e]);
            wHX[mt][e] = (g == 0) ? (short)f2bf(WH_X[j * 8 + e]) : (short)0;
        }
    }

    float bzr[4][4], bhh[2][4], wpr[2][4];
#pragma unroll
    for (int mt = 0; mt < 4; mt++)
#pragma unroll
        for (int r = 0; r < 4; r++) bzr[mt][r] = BZR[mt * 16 + 4 * g + r];
#pragma unroll
    for (int mt = 0; mt < 2; mt++)
#pragma unroll
        for (int r = 0; r < 4; r++) {
            bhh[mt][r] = BH[mt * 16 + 4 * g + r];
            wpr[mt][r] = Wp[mt * 16 + 4 * g + r];
        }

    // softmax(att)
    float am = att[0];
    for (int t = 1; t < 12; t++) am = fmaxf(am, att[t]);
    float ad = 0.0f;
    for (int t = 0; t < 12; t++) ad += __expf(att[t] - am);
    float inv_ad = 1.0f / ad;

    float H[2][4][4], acc[2][4][4];
#pragma unroll
    for (int mt = 0; mt < 2; mt++)
#pragma unroll
        for (int nt = 0; nt < 4; nt++)
#pragma unroll
            for (int r = 0; r < 4; r++) { H[mt][nt][r] = 0.0f; acc[mt][nt][r] = 0.0f; }

    const f32x4 kc = {0.0f, 0.0f, 0.0f, 0.0f};

#pragma unroll 1
    for (int t = 0; t < 12; t++) {
        float pt = __expf(att[t] - am) * inv_ad;

        bf16x8 bH[4], bX[4];
#pragma unroll
        for (int nt = 0; nt < 4; nt++) {
            bH[nt] = *(const bf16x8*)(&sH[(nt * 16 + lo16) * 40 + g * 8]);
            const unsigned short* px = (g == 0) ? &sXp[t * 512 + (nt * 16 + lo16) * 8] : &zblk[0];
            bX[nt] = *(const bf16x8*)px;
        }

        // Z (j' tiles 0,1)
        float Z[2][4][4];
#pragma unroll
        for (int mt = 0; mt < 2; mt++)
#pragma unroll
            for (int nt = 0; nt < 4; nt++) {
                f32x4 d = MFMA_B16(wZRH[mt], bH[nt], kc);
                d = MFMA_B16(wZRX[mt], bX[nt], d);
#pragma unroll
                for (int r = 0; r < 4; r++) Z[mt][nt][r] = sigf(d[r] + bzr[mt][r]);
            }

        // R (tiles 2,3) -> RH, store bf16
#pragma unroll
        for (int mt = 2; mt < 4; mt++)
#pragma unroll
            for (int nt = 0; nt < 4; nt++) {
                f32x4 d = MFMA_B16(wZRH[mt], bH[nt], kc);
                d = MFMA_B16(wZRX[mt], bX[nt], d);
                float rh[4];
#pragma unroll
                for (int r = 0; r < 4; r++)
                    rh[r] = H[mt - 2][nt][r] * sigf(d[r] + bzr[mt][r]);
                uint2 w;
                w.x = (unsigned)f2bf(rh[0]) | ((unsigned)f2bf(rh[1]) << 16);
                w.y = (unsigned)f2bf(rh[2]) | ((unsigned)f2bf(rh[3]) << 16);
                *(uint2*)(&sRH[(nt * 16 + lo16) * 40 + (mt - 2) * 16 + 4 * g]) = w;
            }

        bf16x8 bR[4];
#pragma unroll
        for (int nt = 0; nt < 4; nt++)
            bR[nt] = *(const bf16x8*)(&sRH[(nt * 16 + lo16) * 40 + g * 8]);

        // candidate + update + attention accumulate + H write-back
#pragma unroll
        for (int mt = 0; mt < 2; mt++)
#pragma unroll
            for (int nt = 0; nt < 4; nt++) {
                f32x4 d = MFMA_B16(wHH[mt], bR[nt], kc);
                d = MFMA_B16(wHX[mt], bX[nt], d);
#pragma unroll
                for (int r = 0; r < 4; r++) {
                    float T = tanh_fast(d[r] + bhh[mt][r]);
                    float z = Z[mt][nt][r];
                    float h = T + z * (H[mt][nt][r] - T);
                    H[mt][nt][r] = h;
                    acc[mt][nt][r] += pt * h;
                }
                uint2 w;
                w.x = (unsigned)f2bf(H[mt][nt][0]) | ((unsigned)f2bf(H[mt][nt][1]) << 16);
                w.y = (unsigned)f2bf(H[mt][nt][2]) | ((unsigned)f2bf(H[mt][nt][3]) << 16);
                *(uint2*)(&sH[(nt * 16 + lo16) * 40 + mt * 16 + 4 * g]) = w;
            }
    }

    // epilogue: out[node] = relu( sum_j relu(acc)*Wp + bp + x[node,1,11] )
    float res[4];
#pragma unroll
    for (int nt = 0; nt < 4; nt++) {
        float p = 0.0f;
#pragma unroll
        for (int mt = 0; mt < 2; mt++)
#pragma unroll
            for (int r = 0; r < 4; r++) p += fmaxf(acc[mt][nt][r], 0.0f) * wpr[mt][r];
        p += __shfl_xor(p, 16);
        p += __shfl_xor(p, 32);
        res[nt] = p;
    }
    if (l < 16) {
        float bpv = bp[0];
#pragma unroll
        for (int nt = 0; nt < 4; nt++) {
            int nd = base + nt * 16 + l;
            if (nd < n) out[nd] = fmaxf(res[nt] + bpv + x[(size_t)nd * 96 + 23], 0.0f);
        }
    }
}

// ---------------------------------------------------------------------------
static inline size_t align_up(size_t v, size_t a) { return (v + a - 1) & ~(a - 1); }

extern "C" void kernel_launch(void* const* d_in, const int* in_sizes, int n_in,
                              void* d_out, int out_size, void* d_ws, size_t ws_size,
                              hipStream_t stream) {
    const float* x   = (const float*)d_in[0];
    const int*   ei  = (const int*)d_in[1];
    const float* ew  = (const float*)d_in[2];
    const float* Wz  = (const float*)d_in[3];
    const float* bz  = (const float*)d_in[4];
    const float* Wr  = (const float*)d_in[5];
    const float* br  = (const float*)d_in[6];
    const float* Wh  = (const float*)d_in[7];
    const float* bh  = (const float*)d_in[8];
    const float* Lz  = (const float*)d_in[9];
    const float* lbz = (const float*)d_in[10];
    const float* Lr  = (const float*)d_in[11];
    const float* lbr = (const float*)d_in[12];
    const float* Lh  = (const float*)d_in[13];
    const float* lbh = (const float*)d_in[14];
    const float* att = (const float*)d_in[15];
    const float* Wp  = (const float*)d_in[16];
    const float* bp  = (const float*)d_in[17];
    float* out = (float*)d_out;

    const int N = in_sizes[0] / 96;
    const int E = in_sizes[2];

    char* ws = (char*)d_ws;
    size_t off = 0;
    unsigned long long* pk = (unsigned long long*)(ws + off); off = align_up(off + (size_t)N * 8, 256);
    float* dinv   = (float*)(ws + off); off = align_up(off + (size_t)N * 4, 256);
    int*   rowptr = (int*)  (ws + off); off = align_up(off + (size_t)(N + 1) * 4, 256);
    int*   bsum   = (int*)  (ws + off); off = align_up(off + 2048 * 4, 256);
    int*   boff   = (int*)  (ws + off); off = align_up(off + 2048 * 4, 256);
    uint2* cedge  = (uint2*)(ws + off); off = align_up(off + (size_t)E * 8, 256);
    unsigned short* Xb = (unsigned short*)(ws + off); off = align_up(off + (size_t)N * 96 * 2, 256);
    unsigned short* Xp = (unsigned short*)(ws + off); off = align_up(off + (size_t)N * 96 * 2, 256);
    float* WC     = (float*)(ws + off); off = align_up(off + 3936 * 4, 256);

    // rank[] overlays the Xp region: written by k_edge_pass1, consumed by
    // k_fill, both strictly before k_pull writes Xp (stream-ordered).
    unsigned short* rank = Xp;

    hipMemsetAsync(pk, 0, (size_t)N * 8, stream);

    int eb = (E + 255) / 256;
    int n96_4 = N * 96 / 4;
    int nb1 = (N + 2047) / 2048;

    k_cast<<<(n96_4 + 255) / 256, 256, 0, stream>>>(x, Xb, n96_4);
    k_wprep<<<1, 256, 0, stream>>>(Wz, Wr, Wh, Lz, Lr, Lh, bz, br, bh, lbz, lbr, lbh, WC);
    k_edge_pass1<<<eb, 256, 0, stream>>>(ei, ew, pk, rank, E);
    k_scan1<<<nb1, 256, 0, stream>>>(pk, dinv, rowptr, bsum, N);
    k_scan2<<<1, 256, 0, stream>>>(bsum, boff, nb1);
    k_scan3<<<(N / 4 + 256) / 256 + 1, 256, 0, stream>>>(rowptr, boff, N, E);
    k_fill<<<eb, 256, 0, stream>>>(ei, ew, dinv, rowptr, rank, cedge, E);
    k_pull<<<(N * 4 + 255) / 256, 256, 0, stream>>>(Xb, dinv, rowptr, cedge, Xp, N);
    k_gru<<<(N + 63) / 64, 64, 0, stream>>>(Xp, x, WC, att, Wp, bp, out, N);
}